// Round 1
// baseline (13707.368 us; speedup 1.0000x reference)
//
#include <hip/hip_runtime.h>
#include <hip/hip_bf16.h>

// LSTM seq2seq: B=256, T=256 enc + 256 dec, D_IN=512, HID=OUT=1024.
// Strategy: split-bf16 3-pass MFMA (f32-accurate) fused GEMM+LSTM-cell step
// kernel, launched 512x sequentially; weights pre-split/transposed once.

#define NB   256
#define TSEQ 256
#define DIN  512
#define HID  1024
#define G4   4096

typedef __attribute__((ext_vector_type(8))) __bf16 bf16x8;
typedef __attribute__((ext_vector_type(4))) float  f32x4;

static __device__ __forceinline__ unsigned short f2bf(float v) {
    unsigned u; __builtin_memcpy(&u, &v, 4);
    return (unsigned short)((u + 0x7FFFu + ((u >> 16) & 1u)) >> 16);  // RNE
}
static __device__ __forceinline__ float bf2f(unsigned short b) {
    unsigned u = ((unsigned)b) << 16; float f; __builtin_memcpy(&f, &u, 4); return f;
}

static __device__ __forceinline__ void glds16(const void* g, void* l) {
    __builtin_amdgcn_global_load_lds(
        (const __attribute__((address_space(1))) unsigned int*)g,
        (__attribute__((address_space(3))) unsigned int*)l, 16, 0, 0);
}

// W [K][N] f32 -> WT_hi/WT_lo [N][K] bf16 split (transposed, N-major rows)
__global__ __launch_bounds__(256) void split_transpose(
        const float* __restrict__ W, unsigned short* __restrict__ T_hi,
        unsigned short* __restrict__ T_lo, int K, int N) {
    __shared__ float tile[64][65];
    const int kb = blockIdx.x * 64, nb = blockIdx.y * 64;
    const int tid = threadIdx.x;
    const int r = tid >> 2, c0 = (tid & 3) << 4;
    #pragma unroll
    for (int j = 0; j < 16; j += 4) {
        float4 v = *(const float4*)(W + (size_t)(kb + r) * N + nb + c0 + j);
        tile[r][c0 + j + 0] = v.x; tile[r][c0 + j + 1] = v.y;
        tile[r][c0 + j + 2] = v.z; tile[r][c0 + j + 3] = v.w;
    }
    __syncthreads();
    #pragma unroll
    for (int j = 0; j < 16; ++j) {
        float v = tile[c0 + j][r];
        unsigned short hi = f2bf(v);
        unsigned short lo = f2bf(v - bf2f(hi));
        size_t o = (size_t)(nb + r) * K + kb + c0 + j;
        T_hi[o] = hi; T_lo[o] = lo;
    }
}

// Plain f32 GEMM [256xHID]@[HIDxHID] + bias -> Of32 (+ optional bf16 splits).
// Used once each for h_cur / c_cur init projections.
__global__ __launch_bounds__(256) void proj_gemm(
        const float* __restrict__ A, const float* __restrict__ Bw,
        const float* __restrict__ bias, float* __restrict__ Of32,
        unsigned short* __restrict__ Ohi, unsigned short* __restrict__ Olo,
        int emit) {
    __shared__ float As[64][33];
    __shared__ float Bs[32][65];
    const int nb = blockIdx.x * 64, mb = blockIdx.y * 64;
    const int tid = threadIdx.x;
    const int tm = (tid >> 4) << 2, tn = (tid & 15) << 2;
    float acc[4][4] = {};
    for (int k0 = 0; k0 < HID; k0 += 32) {
        {
            const int r = tid >> 2, c = (tid & 3) << 3;
            float4 a0 = *(const float4*)(A + (size_t)(mb + r) * HID + k0 + c);
            float4 a1 = *(const float4*)(A + (size_t)(mb + r) * HID + k0 + c + 4);
            As[r][c+0]=a0.x; As[r][c+1]=a0.y; As[r][c+2]=a0.z; As[r][c+3]=a0.w;
            As[r][c+4]=a1.x; As[r][c+5]=a1.y; As[r][c+6]=a1.z; As[r][c+7]=a1.w;
            const int rk = tid >> 3, cn = (tid & 7) << 3;
            float4 b0 = *(const float4*)(Bw + (size_t)(k0 + rk) * HID + nb + cn);
            float4 b1 = *(const float4*)(Bw + (size_t)(k0 + rk) * HID + nb + cn + 4);
            Bs[rk][cn+0]=b0.x; Bs[rk][cn+1]=b0.y; Bs[rk][cn+2]=b0.z; Bs[rk][cn+3]=b0.w;
            Bs[rk][cn+4]=b1.x; Bs[rk][cn+5]=b1.y; Bs[rk][cn+6]=b1.z; Bs[rk][cn+7]=b1.w;
        }
        __syncthreads();
        #pragma unroll
        for (int k = 0; k < 32; ++k) {
            float av[4], bv[4];
            #pragma unroll
            for (int q = 0; q < 4; ++q) av[q] = As[tm + q][k];
            #pragma unroll
            for (int q = 0; q < 4; ++q) bv[q] = Bs[k][tn + q];
            #pragma unroll
            for (int i = 0; i < 4; ++i)
                #pragma unroll
                for (int j = 0; j < 4; ++j) acc[i][j] += av[i] * bv[j];
        }
        __syncthreads();
    }
    #pragma unroll
    for (int i = 0; i < 4; ++i)
        #pragma unroll
        for (int j = 0; j < 4; ++j) {
            const int m = mb + tm + i, n = nb + tn + j;
            const float v = acc[i][j] + bias[n];
            const size_t o = (size_t)m * HID + n;
            Of32[o] = v;
            if (emit) {
                const unsigned short hi = f2bf(v);
                Ohi[o] = hi; Olo[o] = f2bf(v - bf2f(hi));
            }
        }
}

// LDS staging: 4 arrays (A_hi, A_lo, B_hi, B_lo), each 2 buffers of 8KB.
// Tile layout per buffer: [64 rows][64 k] bf16, byte = row*128 + ((k*2)^((row&7)<<4)).
#define SM_AHI 0
#define SM_ALO 16384
#define SM_BHI 32768
#define SM_BLO 49152

// MODE: 0 = encoder step (x folded, K=1536), 1 = decoder step (pre=dec_const),
//       2 = GEMM-only (dec_const = h_enc @ dec_W[0:1024] + dec_b)
template<int MODE>
__global__ __launch_bounds__(256) void lstm_step(
        const unsigned short* __restrict__ WT_hi, const unsigned short* __restrict__ WT_lo,
        int Kw,
        const unsigned short* __restrict__ h_hi, const unsigned short* __restrict__ h_lo,
        const float* __restrict__ x, int tstep,
        const float* __restrict__ pre, const float* __restrict__ bias,
        const float* c_in, float* c_out,
        float* __restrict__ hout_f32, unsigned short* __restrict__ hout_hi,
        unsigned short* __restrict__ hout_lo, float* __restrict__ out) {
    __shared__ __align__(16) char smem[65536];
    __shared__ float sG[64][68];
    const int wg   = blockIdx.x;
    const int row0 = (wg >> 6) << 6;   // 4 m-blocks of 64 rows
    const int hc0  = (wg & 63) << 4;   // 64 h-col blocks of 16 (n%8 -> same XCD for B reuse)
    const int tid  = threadIdx.x;
    const int lane = tid & 63;
    const int wv   = tid >> 6;
    const int rA   = (wv >> 1) << 5;   // wave row offset within WG: 0/32
    const int cB   = (wv & 1) << 5;    // wave gate-col offset within WG: 0/32

    const int nchunks = (MODE == 0) ? 24 : 16;
    const int kwbase  = (MODE == 1) ? 1024 : 0;

    auto stage = [&](int c, int buf) {
        const int k0 = kwbase + (c << 6);   // W-row base of this chunk
        {   // B: gate strips, wave wv stages gate wv's 16 cols (global_load_lds, swizzled src)
            char* dhb = smem + SM_BHI + buf * 8192;
            char* dlb = smem + SM_BLO + buf * 8192;
            #pragma unroll
            for (int j = 0; j < 2; ++j) {
                const int gclb = (wv << 4) + (j << 3);
                const int gcl  = gclb + (lane >> 3);
                const int kseg = (lane & 7) ^ ((lane >> 3) & 7);
                const size_t go = (size_t)(wv * HID + hc0 + (gcl & 15)) * Kw + k0 + (kseg << 3);
                glds16(WT_hi + go, dhb + (gclb << 7));
                glds16(WT_lo + go, dlb + (gclb << 7));
            }
        }
        if (MODE == 0 && c < 8) {
            // A = x_t chunk: load f32, split to hi/lo in-register, swizzled ds_write
            const int m  = tid >> 2;
            const int kc = (tid & 3) << 4;
            const float* xs = x + ((size_t)(row0 + m) * TSEQ + tstep) * DIN + (c << 6) + kc;
            float v[16];
            #pragma unroll
            for (int q = 0; q < 4; ++q) {
                float4 f = *(const float4*)(xs + (q << 2));
                v[q*4+0] = f.x; v[q*4+1] = f.y; v[q*4+2] = f.z; v[q*4+3] = f.w;
            }
            char* dha = smem + SM_AHI + buf * 8192;
            char* dla = smem + SM_ALO + buf * 8192;
            #pragma unroll
            for (int jj = 0; jj < 16; jj += 2) {
                const unsigned short h0 = f2bf(v[jj]);
                const unsigned short l0 = f2bf(v[jj] - bf2f(h0));
                const unsigned short h1 = f2bf(v[jj+1]);
                const unsigned short l1 = f2bf(v[jj+1] - bf2f(h1));
                const int bo = (m << 7) + ((((kc + jj) << 1)) ^ ((m & 7) << 4));
                *(unsigned*)(dha + bo) = (unsigned)h0 | ((unsigned)h1 << 16);
                *(unsigned*)(dla + bo) = (unsigned)l0 | ((unsigned)l1 << 16);
            }
        } else {
            // A = h split chunk (global_load_lds, swizzled src)
            const int kh = (MODE == 0) ? ((c - 8) << 6) : (c << 6);
            char* dha = smem + SM_AHI + buf * 8192;
            char* dla = smem + SM_ALO + buf * 8192;
            #pragma unroll
            for (int j = 0; j < 2; ++j) {
                const int mb2  = (wv << 4) + (j << 3);
                const int m    = mb2 + (lane >> 3);
                const int kseg = (lane & 7) ^ ((lane >> 3) & 7);
                const size_t go = (size_t)(row0 + m) * HID + kh + (kseg << 3);
                glds16(h_hi + go, dha + (mb2 << 7));
                glds16(h_lo + go, dla + (mb2 << 7));
            }
        }
    };

    f32x4 acc[2][2];
    {
        f32x4 z; z[0] = 0.f; z[1] = 0.f; z[2] = 0.f; z[3] = 0.f;
        acc[0][0] = z; acc[0][1] = z; acc[1][0] = z; acc[1][1] = z;
    }

    stage(0, 0);
    asm volatile("s_waitcnt vmcnt(0)" ::: "memory");
    __syncthreads();

    for (int c = 0; c < nchunks; ++c) {
        const int buf = c & 1;
        if (c + 1 < nchunks) stage(c + 1, buf ^ 1);
        const char* sah = smem + SM_AHI + buf * 8192;
        const char* sal = smem + SM_ALO + buf * 8192;
        const char* sbh = smem + SM_BHI + buf * 8192;
        const char* sbl = smem + SM_BLO + buf * 8192;
        #pragma unroll
        for (int kk = 0; kk < 2; ++kk) {
            const int kb = (kk << 6) | ((lane >> 4) << 4);
            bf16x8 ah[2], al[2], bh[2], bl[2];
            #pragma unroll
            for (int ms = 0; ms < 2; ++ms) {
                const int m  = rA + (ms << 4) + (lane & 15);
                const int ad = (m << 7) + (kb ^ ((m & 7) << 4));
                ah[ms] = *(const bf16x8*)(sah + ad);
                al[ms] = *(const bf16x8*)(sal + ad);
            }
            #pragma unroll
            for (int ns = 0; ns < 2; ++ns) {
                const int gcl = cB + (ns << 4) + (lane & 15);
                const int ad  = (gcl << 7) + (kb ^ ((gcl & 7) << 4));
                bh[ns] = *(const bf16x8*)(sbh + ad);
                bl[ns] = *(const bf16x8*)(sbl + ad);
            }
            #pragma unroll
            for (int ms = 0; ms < 2; ++ms)
                #pragma unroll
                for (int ns = 0; ns < 2; ++ns) {
                    acc[ms][ns] = __builtin_amdgcn_mfma_f32_16x16x32_bf16(ah[ms], bh[ns], acc[ms][ns], 0, 0, 0);
                    acc[ms][ns] = __builtin_amdgcn_mfma_f32_16x16x32_bf16(al[ms], bh[ns], acc[ms][ns], 0, 0, 0);
                    acc[ms][ns] = __builtin_amdgcn_mfma_f32_16x16x32_bf16(ah[ms], bl[ns], acc[ms][ns], 0, 0, 0);
                }
        }
        asm volatile("s_waitcnt vmcnt(0)" ::: "memory");
        __syncthreads();
    }

    // C/D layout (HW-verified): col = lane&15, row = (lane>>4)*4 + reg
    if (MODE == 2) {
        #pragma unroll
        for (int ms = 0; ms < 2; ++ms)
            #pragma unroll
            for (int ns = 0; ns < 2; ++ns)
                #pragma unroll
                for (int r = 0; r < 4; ++r) {
                    const int mloc = rA + (ms << 4) + ((lane >> 4) << 2) + r;
                    const int gcl  = cB + (ns << 4) + (lane & 15);
                    const int gcol = (gcl >> 4) * HID + hc0 + (gcl & 15);
                    out[(size_t)(row0 + mloc) * G4 + gcol] = acc[ms][ns][r] + bias[gcol];
                }
        return;
    }

    #pragma unroll
    for (int ms = 0; ms < 2; ++ms)
        #pragma unroll
        for (int ns = 0; ns < 2; ++ns)
            #pragma unroll
            for (int r = 0; r < 4; ++r) {
                const int mloc = rA + (ms << 4) + ((lane >> 4) << 2) + r;
                const int gcl  = cB + (ns << 4) + (lane & 15);
                sG[gcl][mloc] = acc[ms][ns][r];
            }
    __syncthreads();

    // fused LSTM cell update: 64 rows x 16 h-cols per WG, 4 cells/thread
    const int n  = tid & 15;
    const int mq = tid >> 4;
    #pragma unroll
    for (int q = 0; q < 4; ++q) {
        const int m = mq + (q << 4);
        const int grow = row0 + m;
        float gi = sG[n][m];
        float gf = sG[16 + n][m];
        float go = sG[32 + n][m];
        float gg = sG[48 + n][m];
        if (MODE == 1) {
            const float* p = pre + (size_t)grow * G4 + hc0 + n;
            gi += p[0]; gf += p[HID]; go += p[2 * HID]; gg += p[3 * HID];
        } else {
            gi += bias[hc0 + n];           gf += bias[HID + hc0 + n];
            go += bias[2 * HID + hc0 + n]; gg += bias[3 * HID + hc0 + n];
        }
        const float si = 1.f / (1.f + expf(-gi));
        const float sf = 1.f / (1.f + expf(-gf));
        const float so = 1.f / (1.f + expf(-go));
        const float tg = tanhf(gg);
        const size_t ci = (size_t)grow * HID + hc0 + n;
        const float cnew = sf * c_in[ci] + si * tg;
        c_out[ci] = cnew;
        const float hnew = so * tanhf(cnew);
        hout_f32[ci] = hnew;
        const unsigned short hh = f2bf(hnew);
        hout_hi[ci] = hh;
        hout_lo[ci] = f2bf(hnew - bf2f(hh));
        if (MODE == 1) out[((size_t)grow * TSEQ + tstep) * HID + hc0 + n] = hnew;
    }
}

extern "C" void kernel_launch(void* const* d_in, const int* in_sizes, int n_in,
                              void* d_out, int out_size, void* d_ws, size_t ws_size,
                              hipStream_t stream) {
    (void)in_sizes; (void)n_in; (void)out_size;
    const float* x     = (const float*)d_in[0];
    const float* enc_W = (const float*)d_in[1];
    const float* enc_b = (const float*)d_in[2];
    const float* dec_W = (const float*)d_in[3];
    const float* dec_b = (const float*)d_in[4];
    const float* Wh    = (const float*)d_in[5];
    const float* bh    = (const float*)d_in[6];
    const float* Wc    = (const float*)d_in[7];
    const float* bc    = (const float*)d_in[8];
    float* out = (float*)d_out;

    char* w = (char*)d_ws;
    size_t off = 0;
    auto alloc = [&](size_t bytes) -> void* {
        off = (off + 255) & ~(size_t)255;
        void* p = w + off;
        off += bytes;
        return p;
    };
    unsigned short* encT_hi = (unsigned short*)alloc((size_t)G4 * 1536 * 2);
    unsigned short* encT_lo = (unsigned short*)alloc((size_t)G4 * 1536 * 2);
    unsigned short* decT_hi = (unsigned short*)alloc((size_t)G4 * 2048 * 2);
    unsigned short* decT_lo = (unsigned short*)alloc((size_t)G4 * 2048 * 2);
    float* c0     = (float*)alloc((size_t)NB * HID * 4);
    float* c1     = (float*)alloc((size_t)NB * HID * 4);
    float* dconst = (float*)alloc((size_t)NB * G4 * 4);
    float* hf[2]; unsigned short* hhi[2]; unsigned short* hlo[2];
    for (int i = 0; i < 2; ++i) {
        hf[i]  = (float*)alloc((size_t)NB * HID * 4);
        hhi[i] = (unsigned short*)alloc((size_t)NB * HID * 2);
        hlo[i] = (unsigned short*)alloc((size_t)NB * HID * 2);
    }
    if (off > ws_size) return;  // ~66MB required; fail loudly if workspace too small

    split_transpose<<<dim3(1536 / 64, 64), 256, 0, stream>>>(enc_W, encT_hi, encT_lo, 1536, G4);
    split_transpose<<<dim3(2048 / 64, 64), 256, 0, stream>>>(dec_W, decT_hi, decT_lo, 2048, G4);
    (void)hipMemsetAsync(hhi[0], 0, (size_t)NB * HID * 2, stream);
    (void)hipMemsetAsync(hlo[0], 0, (size_t)NB * HID * 2, stream);
    (void)hipMemsetAsync(c0,     0, (size_t)NB * HID * 4, stream);

    // ---- encoder: 256 sequential fused steps (x folded into K) ----
    for (int t = 0; t < TSEQ; ++t) {
        const int i = t & 1, o = i ^ 1;
        lstm_step<0><<<256, 256, 0, stream>>>(encT_hi, encT_lo, 1536,
            hhi[i], hlo[i], x, t, nullptr, enc_b, c0, c0,
            hf[o], hhi[o], hlo[o], nullptr);
    }
    // h_enc splits are in buf 0 (t=255 writes buf 0); c_enc in c0.
    // dec_const = h_enc @ dec_W[0:1024] + dec_b  (constant decoder input term)
    lstm_step<2><<<256, 256, 0, stream>>>(decT_hi, decT_lo, 2048,
        hhi[0], hlo[0], nullptr, 0, nullptr, dec_b, nullptr, nullptr,
        nullptr, nullptr, nullptr, dconst);
    // h_cur = h_enc @ Wh + bh -> buf1 (with splits); c_cur = c_enc @ Wc + bc -> c1
    proj_gemm<<<dim3(16, 4), 256, 0, stream>>>(hf[0], Wh, bh, hf[1], hhi[1], hlo[1], 1);
    proj_gemm<<<dim3(16, 4), 256, 0, stream>>>(c0, Wc, bc, c1, nullptr, nullptr, 0);

    // ---- decoder: 256 sequential fused steps, h written to out each step ----
    for (int t = 0; t < TSEQ; ++t) {
        const int i = (t & 1) ^ 1, o = t & 1;
        lstm_step<1><<<256, 256, 0, stream>>>(decT_hi, decT_lo, 2048,
            hhi[i], hlo[i], nullptr, t, dconst, nullptr, c1, c1,
            hf[o], hhi[o], hlo[o], out);
    }
}